// Round 1
// baseline (1950.385 us; speedup 1.0000x reference)
//
#include <hip/hip_runtime.h>
#include <math.h>

#define BATCH 16
#define HF 1024
#define WF 1024
#define HS 512
#define WS2 512
#define HC 256
#define WC 256
#define KMAX 32
#define CAP 16384
#define CROPSZ 160

// ---- workspace byte offsets ----
#define OFF_IMGS 0UL                                   // 16*512*512 f32 = 16 MB
#define OFF_CMS  16777216UL                            // 16*256*256 f32 = 4 MB
#define OFF_KEYS 20971520UL                            // 16*16384 u64  = 2 MB
#define OFF_CNT  23068672UL                            // 16 int
#define OFF_CX   23068736UL                            // 512 f32
#define OFF_CY   (OFF_CX + 2048UL)
#define OFF_VLD  (OFF_CY + 2048UL)

// ---- output element offsets ----
#define OUT_CROPS 0
#define OUT_OFFS  13107200
#define OUT_VALS  13108224
#define OUT_VALID 13108736

__global__ void init_kernel(int* counts) {
    if (threadIdx.x < BATCH) counts[threadIdx.x] = 0;
}

// jax.image.resize(bilinear, antialias=True) at scale 0.5:
// separable 4-tap triangle filter, weights {1,3,3,1}/8, edge-renormalized.
__global__ __launch_bounds__(256) void resize_kernel(const float* __restrict__ full,
                                                     float* __restrict__ imgs) {
    int i = blockIdx.x * 256 + threadIdx.x;       // 16*512*512 total
    int x = i & (WS2 - 1);
    int y = (i >> 9) & (HS - 1);
    int b = i >> 18;
    const float w4[4] = {0.125f, 0.375f, 0.375f, 0.125f};
    float wy[4], wx[4];
    int ry[4], rx[4];
    float sy = 0.f, sx = 0.f;
#pragma unroll
    for (int j = 0; j < 4; ++j) {
        int r = 2 * y - 1 + j;
        float w = (r >= 0 && r < HF) ? w4[j] : 0.f;
        wy[j] = w; sy += w;
        ry[j] = r < 0 ? 0 : (r >= HF ? HF - 1 : r);
        int c = 2 * x - 1 + j;
        float wc = (c >= 0 && c < WF) ? w4[j] : 0.f;
        wx[j] = wc; sx += wc;
        rx[j] = c < 0 ? 0 : (c >= WF ? WF - 1 : c);
    }
    float inv = 1.f / (sy * sx);
    const float* base = full + ((size_t)b << 20);
    float acc = 0.f;
#pragma unroll
    for (int j = 0; j < 4; ++j) {
        const float* rp = base + ry[j] * WF;
        float rowacc = 0.f;
#pragma unroll
        for (int ii = 0; ii < 4; ++ii) rowacc += wx[ii] * rp[rx[ii]];
        acc += wy[j] * rowacc;
    }
    imgs[i] = acc * inv;
}

// Fused: conv1 5x5 s2 SAME (1->32) + relu, conv2 5x5 s1 SAME (32->1) + sigmoid.
// One block computes a 16x16 cms tile. h tile 20x20x32 in LDS (stride 33 pad).
__global__ __launch_bounds__(256) void conv_fused_kernel(
    const float* __restrict__ imgs, const float* __restrict__ w1,
    const float* __restrict__ b1, const float* __restrict__ w2,
    const float* __restrict__ b2, float* __restrict__ cms) {
    __shared__ float simg[43][43];
    __shared__ float sw1[800];
    __shared__ float sb1[32];
    __shared__ float sh[20 * 20 * 33];
    int tid = threadIdx.x;
    int b = blockIdx.y;
    int ty = blockIdx.x >> 4, tx = blockIdx.x & 15;
    int Y0 = ty << 4, X0 = tx << 4;

    for (int i = tid; i < 800; i += 256) sw1[i] = w1[i];
    if (tid < 32) sb1[tid] = b1[tid];

    int r0 = 2 * Y0 - 5, c0 = 2 * X0 - 5;
    for (int i = tid; i < 43 * 43; i += 256) {
        int r = i / 43, c = i - r * 43;
        int gr = r0 + r, gc = c0 + c;
        float v = 0.f;
        if (gr >= 0 && gr < HS && gc >= 0 && gc < WS2)
            v = imgs[((size_t)b << 18) + gr * WS2 + gc];
        simg[r][c] = v;
    }
    __syncthreads();

    // h tile: h[yh][xh][c], yh = Y0-2+yy ; OOB h rows/cols are ZERO (conv2 pads h)
    for (int p = tid; p < 400; p += 256) {
        int yy = p / 20, xx = p - yy * 20;
        int yh = Y0 - 2 + yy, xh = X0 - 2 + xx;
        if (yh >= 0 && yh < HC && xh >= 0 && xh < WC) {
            float acc[32];
#pragma unroll
            for (int c = 0; c < 32; ++c) acc[c] = sb1[c];
#pragma unroll
            for (int ky = 0; ky < 5; ++ky)
#pragma unroll
                for (int kx = 0; kx < 5; ++kx) {
                    float v = simg[2 * yy + ky][2 * xx + kx];
                    const float* wp = &sw1[(ky * 5 + kx) * 32];
#pragma unroll
                    for (int c = 0; c < 32; ++c) acc[c] += v * wp[c];
                }
#pragma unroll
            for (int c = 0; c < 32; ++c) sh[p * 33 + c] = fmaxf(acc[c], 0.f);
        } else {
#pragma unroll
            for (int c = 0; c < 32; ++c) sh[p * 33 + c] = 0.f;
        }
    }
    __syncthreads();

    {
        int yy = tid >> 4, xx = tid & 15;
        float z = b2[0];
#pragma unroll
        for (int ky = 0; ky < 5; ++ky)
#pragma unroll
            for (int kx = 0; kx < 5; ++kx) {
                const float* hp = &sh[((yy + ky) * 20 + (xx + kx)) * 33];
                const float* wp = &w2[(ky * 5 + kx) * 32];
#pragma unroll
                for (int c = 0; c < 32; ++c) z += hp[c] * wp[c];
            }
        float s = 1.f / (1.f + expf(-z));
        cms[((size_t)b << 16) + (Y0 + yy) * WC + (X0 + xx)] = s;
    }
}

// 3x3 NMS (>=, OOB=-inf) + threshold; emit sortable key per peak.
// key = (f32bits(val)<<32) | (0xFFFFFFFF - idx): unsigned max == (max val, min idx)
__global__ __launch_bounds__(256) void peak_scan_kernel(
    const float* __restrict__ cms, unsigned long long* __restrict__ keys,
    int* __restrict__ counts) {
    int g = blockIdx.x * 256 + threadIdx.x;   // 16*65536
    int b = g >> 16;
    int i = g & 65535;
    int y = i >> 8, x = i & 255;
    const float* cb = cms + ((size_t)b << 16);
    float c = cb[i];
    if (!(c > 0.2f)) return;
    bool peak = true;
#pragma unroll
    for (int dy = -1; dy <= 1; ++dy)
#pragma unroll
        for (int dx = -1; dx <= 1; ++dx) {
            if (dy == 0 && dx == 0) continue;
            int ny = y + dy, nx = x + dx;
            if (ny < 0 || ny >= HC || nx < 0 || nx >= WC) continue;
            if (cb[ny * WC + nx] > c) peak = false;
        }
    if (!peak) return;
    int p = atomicAdd(&counts[b], 1);
    if (p < CAP) {
        unsigned long long key =
            ((unsigned long long)__float_as_uint(c) << 32) |
            (unsigned long long)(0xFFFFFFFFu - (unsigned)i);
        keys[(size_t)b * CAP + p] = key;
    }
}

// One block per batch: 32 rounds of block-wide argmax (exact top_k semantics),
// then integral refinement (5x5, zero outside) and coordinate mapping.
__global__ __launch_bounds__(256) void topk_refine_kernel(
    const float* __restrict__ cms, unsigned long long* __restrict__ keys,
    const int* __restrict__ counts, float* __restrict__ out_off,
    float* __restrict__ out_vals, float* __restrict__ out_valid,
    float* __restrict__ ws_cx, float* __restrict__ ws_cy,
    float* __restrict__ ws_v) {
    int b = blockIdx.x;
    int tid = threadIdx.x;
    __shared__ unsigned long long rkey[256];
    __shared__ int rpos[256];
    __shared__ unsigned long long sel[KMAX];
    int cnt = counts[b]; if (cnt > CAP) cnt = CAP;
    unsigned long long* kb = keys + (size_t)b * CAP;

    for (int k = 0; k < KMAX; ++k) {
        unsigned long long best = 0ULL; int bp = -1;
        for (int p = tid; p < cnt; p += 256) {
            unsigned long long kk = kb[p];
            if (kk > best) { best = kk; bp = p; }
        }
        rkey[tid] = best; rpos[tid] = bp;
        __syncthreads();
        for (int s = 128; s > 0; s >>= 1) {
            if (tid < s && rkey[tid + s] > rkey[tid]) {
                rkey[tid] = rkey[tid + s]; rpos[tid] = rpos[tid + s];
            }
            __syncthreads();
        }
        if (tid == 0) { sel[k] = rkey[0]; if (rkey[0]) kb[rpos[0]] = 0ULL; }
        __syncthreads();
    }

    if (tid < KMAX) {
        int k = tid;
        unsigned long long key = sel[k];
        bool valid = key != 0ULL;
        float cx = 80.f, cy = 80.f, val = 0.f;
        if (valid) {
            val = __uint_as_float((unsigned)(key >> 32));
            int idx = (int)(0xFFFFFFFFu - (unsigned)(key & 0xFFFFFFFFULL));
            int py = idx >> 8, px = idx & 255;
            const float* cb = cms + ((size_t)b << 16);
            float gv = 1e-12f, sdx = 0.f, sdy = 0.f;
#pragma unroll
            for (int oy = -2; oy <= 2; ++oy)
#pragma unroll
                for (int ox = -2; ox <= 2; ++ox) {
                    int yy = py + oy, xx = px + ox;
                    if (yy < 0 || yy >= HC || xx < 0 || xx >= WC) continue;
                    float pv = cb[yy * WC + xx];
                    gv += pv; sdx += pv * (float)ox; sdy += pv * (float)oy;
                }
            float dx = sdx / gv, dy = sdy / gv;
            cx = ((float)px + dx) * 4.f;
            cy = ((float)py + dy) * 4.f;
        }
        int o = b * KMAX + k;
        out_off[o * 2 + 0] = cx - 80.f;
        out_off[o * 2 + 1] = cy - 80.f;
        out_vals[o] = val;
        out_valid[o] = valid ? 1.f : 0.f;
        ws_cx[o] = cx; ws_cy[o] = cy; ws_v[o] = valid ? 1.f : 0.f;
    }
}

// 160x160 bilinear crop from full image; zero outside image or for invalid peaks.
__global__ __launch_bounds__(256) void crop_kernel(
    const float* __restrict__ full, const float* __restrict__ ws_cx,
    const float* __restrict__ ws_cy, const float* __restrict__ ws_v,
    float* __restrict__ out_crops) {
    int bidx = blockIdx.x;                      // 512 crops * 100 blocks
    int cid = bidx / 100;
    int pp = (bidx - cid * 100) * 256 + threadIdx.x;   // 0..25599
    int b = cid >> 5;
    float cx = ws_cx[cid], cy = ws_cy[cid], v = ws_v[cid];
    int row = pp / CROPSZ, col = pp - row * CROPSZ;
    float sy = cy - 79.5f + (float)row;
    float sx = cx - 79.5f + (float)col;
    float y0f = floorf(sy), x0f = floorf(sx);
    float wy = sy - y0f, wx = sx - x0f;
    int y0 = (int)y0f, x0 = (int)x0f;
    int yi0 = min(max(y0, 0), HF - 1);
    int yi1 = min(max(y0 + 1, 0), HF - 1);
    int xi0 = min(max(x0, 0), WF - 1);
    int xi1 = min(max(x0 + 1, 0), WF - 1);
    const float* base = full + ((size_t)b << 20);
    float t00 = base[yi0 * WF + xi0];
    float t01 = base[yi0 * WF + xi1];
    float t10 = base[yi1 * WF + xi0];
    float t11 = base[yi1 * WF + xi1];
    float top = t00 * (1.f - wx) + t01 * wx;
    float bot = t10 * (1.f - wx) + t11 * wx;
    float val = top * (1.f - wy) + bot * wy;
    float inr = (sy >= 0.f && sy <= (float)(HF - 1) &&
                 sx >= 0.f && sx <= (float)(WF - 1)) ? 1.f : 0.f;
    out_crops[(size_t)cid * (CROPSZ * CROPSZ) + pp] = val * inr * v;
}

extern "C" void kernel_launch(void* const* d_in, const int* in_sizes, int n_in,
                              void* d_out, int out_size, void* d_ws, size_t ws_size,
                              hipStream_t stream) {
    const float* full = (const float*)d_in[0];
    const float* w1   = (const float*)d_in[1];
    const float* b1   = (const float*)d_in[2];
    const float* w2   = (const float*)d_in[3];
    const float* b2   = (const float*)d_in[4];

    char* ws = (char*)d_ws;
    float* imgs = (float*)(ws + OFF_IMGS);
    float* cms  = (float*)(ws + OFF_CMS);
    unsigned long long* keys = (unsigned long long*)(ws + OFF_KEYS);
    int* counts = (int*)(ws + OFF_CNT);
    float* ws_cx = (float*)(ws + OFF_CX);
    float* ws_cy = (float*)(ws + OFF_CY);
    float* ws_v  = (float*)(ws + OFF_VLD);

    float* out = (float*)d_out;
    float* out_crops = out + OUT_CROPS;
    float* out_off   = out + OUT_OFFS;
    float* out_vals  = out + OUT_VALS;
    float* out_valid = out + OUT_VALID;

    hipLaunchKernelGGL(init_kernel, dim3(1), dim3(64), 0, stream, counts);
    hipLaunchKernelGGL(resize_kernel, dim3(16384), dim3(256), 0, stream, full, imgs);
    hipLaunchKernelGGL(conv_fused_kernel, dim3(256, 16), dim3(256), 0, stream,
                       imgs, w1, b1, w2, b2, cms);
    hipLaunchKernelGGL(peak_scan_kernel, dim3(4096), dim3(256), 0, stream,
                       cms, keys, counts);
    hipLaunchKernelGGL(topk_refine_kernel, dim3(16), dim3(256), 0, stream,
                       cms, keys, counts, out_off, out_vals, out_valid,
                       ws_cx, ws_cy, ws_v);
    hipLaunchKernelGGL(crop_kernel, dim3(51200), dim3(256), 0, stream,
                       full, ws_cx, ws_cy, ws_v, out_crops);
}

// Round 2
// 736.425 us; speedup vs baseline: 2.6485x; 2.6485x over previous
//
#include <hip/hip_runtime.h>
#include <math.h>

#define BATCH 16
#define HF 1024
#define WF 1024
#define HS 512
#define WS2 512
#define HC 256
#define WC 256
#define KMAX 32
#define CAP 16384
#define CROPSZ 160
#define CNT_STRIDE 16   // pad counters to 64B so the 16 batch counters live in different cache lines

// ---- workspace byte offsets ----
#define OFF_IMGS 0UL                                   // 16*512*512 f32 = 16 MB
#define OFF_CMS  16777216UL                            // 16*256*256 f32 = 4 MB
#define OFF_KEYS 20971520UL                            // 16*16384 u64  = 2 MB
#define OFF_CNT  23068672UL                            // 16*16 int
#define OFF_CX   23070720UL                            // 512 f32
#define OFF_CY   (OFF_CX + 2048UL)
#define OFF_VLD  (OFF_CY + 2048UL)

// ---- output element offsets ----
#define OUT_CROPS 0
#define OUT_OFFS  13107200
#define OUT_VALS  13108224
#define OUT_VALID 13108736

__global__ void init_kernel(int* counts) {
    if (threadIdx.x < BATCH * CNT_STRIDE) counts[threadIdx.x] = 0;
}

// jax.image.resize(bilinear, antialias=True) at scale 0.5:
// separable 4-tap triangle filter, weights {1,3,3,1}/8, edge-renormalized.
__global__ __launch_bounds__(256) void resize_kernel(const float* __restrict__ full,
                                                     float* __restrict__ imgs) {
    int i = blockIdx.x * 256 + threadIdx.x;       // 16*512*512 total
    int x = i & (WS2 - 1);
    int y = (i >> 9) & (HS - 1);
    int b = i >> 18;
    const float w4[4] = {0.125f, 0.375f, 0.375f, 0.125f};
    float wy[4], wx[4];
    int ry[4], rx[4];
    float sy = 0.f, sx = 0.f;
#pragma unroll
    for (int j = 0; j < 4; ++j) {
        int r = 2 * y - 1 + j;
        float w = (r >= 0 && r < HF) ? w4[j] : 0.f;
        wy[j] = w; sy += w;
        ry[j] = r < 0 ? 0 : (r >= HF ? HF - 1 : r);
        int c = 2 * x - 1 + j;
        float wc = (c >= 0 && c < WF) ? w4[j] : 0.f;
        wx[j] = wc; sx += wc;
        rx[j] = c < 0 ? 0 : (c >= WF ? WF - 1 : c);
    }
    float inv = 1.f / (sy * sx);
    const float* base = full + ((size_t)b << 20);
    float acc = 0.f;
#pragma unroll
    for (int j = 0; j < 4; ++j) {
        const float* rp = base + ry[j] * WF;
        float rowacc = 0.f;
#pragma unroll
        for (int ii = 0; ii < 4; ++ii) rowacc += wx[ii] * rp[rx[ii]];
        acc += wy[j] * rowacc;
    }
    imgs[i] = acc * inv;
}

// Fused: conv1 5x5 s2 SAME (1->32) + relu, conv2 5x5 s1 SAME (32->1) + sigmoid.
// One block computes a 16x16 cms tile. h tile 20x20x32 in LDS (stride 33 pad).
__global__ __launch_bounds__(256) void conv_fused_kernel(
    const float* __restrict__ imgs, const float* __restrict__ w1,
    const float* __restrict__ b1, const float* __restrict__ w2,
    const float* __restrict__ b2, float* __restrict__ cms) {
    __shared__ float simg[43][43];
    __shared__ float sw1[800];
    __shared__ float sb1[32];
    __shared__ float sh[20 * 20 * 33];
    int tid = threadIdx.x;
    int b = blockIdx.y;
    int ty = blockIdx.x >> 4, tx = blockIdx.x & 15;
    int Y0 = ty << 4, X0 = tx << 4;

    for (int i = tid; i < 800; i += 256) sw1[i] = w1[i];
    if (tid < 32) sb1[tid] = b1[tid];

    int r0 = 2 * Y0 - 5, c0 = 2 * X0 - 5;
    for (int i = tid; i < 43 * 43; i += 256) {
        int r = i / 43, c = i - r * 43;
        int gr = r0 + r, gc = c0 + c;
        float v = 0.f;
        if (gr >= 0 && gr < HS && gc >= 0 && gc < WS2)
            v = imgs[((size_t)b << 18) + gr * WS2 + gc];
        simg[r][c] = v;
    }
    __syncthreads();

    // h tile: h[yh][xh][c], yh = Y0-2+yy ; OOB h rows/cols are ZERO (conv2 pads h)
    for (int p = tid; p < 400; p += 256) {
        int yy = p / 20, xx = p - yy * 20;
        int yh = Y0 - 2 + yy, xh = X0 - 2 + xx;
        if (yh >= 0 && yh < HC && xh >= 0 && xh < WC) {
            float acc[32];
#pragma unroll
            for (int c = 0; c < 32; ++c) acc[c] = sb1[c];
#pragma unroll
            for (int ky = 0; ky < 5; ++ky)
#pragma unroll
                for (int kx = 0; kx < 5; ++kx) {
                    float v = simg[2 * yy + ky][2 * xx + kx];
                    const float* wp = &sw1[(ky * 5 + kx) * 32];
#pragma unroll
                    for (int c = 0; c < 32; ++c) acc[c] += v * wp[c];
                }
#pragma unroll
            for (int c = 0; c < 32; ++c) sh[p * 33 + c] = fmaxf(acc[c], 0.f);
        } else {
#pragma unroll
            for (int c = 0; c < 32; ++c) sh[p * 33 + c] = 0.f;
        }
    }
    __syncthreads();

    {
        int yy = tid >> 4, xx = tid & 15;
        float z = b2[0];
#pragma unroll
        for (int ky = 0; ky < 5; ++ky)
#pragma unroll
            for (int kx = 0; kx < 5; ++kx) {
                const float* hp = &sh[((yy + ky) * 20 + (xx + kx)) * 33];
                const float* wp = &w2[(ky * 5 + kx) * 32];
#pragma unroll
                for (int c = 0; c < 32; ++c) z += hp[c] * wp[c];
            }
        float s = 1.f / (1.f + expf(-z));
        cms[((size_t)b << 16) + (Y0 + yy) * WC + (X0 + xx)] = s;
    }
}

// 3x3 NMS (>=, OOB ignored) + threshold; LDS row staging + LDS prefix,
// ONE global atomic per block (row). key = (f32bits(val)<<32) | (~idx):
// unsigned max == (max val, min idx) — exact top_k tie-break.
__global__ __launch_bounds__(256) void peak_scan_kernel(
    const float* __restrict__ cms, unsigned long long* __restrict__ keys,
    int* __restrict__ counts) {
    int b = blockIdx.x >> 8;          // 16*256 blocks: one per conf-map row
    int y = blockIdx.x & 255;
    int x = threadIdx.x;              // one thread per column
    const float* cb = cms + ((size_t)b << 16);
    __shared__ float rows[3][256];
    __shared__ int lcnt, lbase;
    if (x == 0) lcnt = 0;
#pragma unroll
    for (int j = 0; j < 3; ++j) {
        int yy = y - 1 + j;
        rows[j][x] = (yy >= 0 && yy < HC) ? cb[yy * WC + x] : -INFINITY;
    }
    __syncthreads();
    float c = rows[1][x];
    bool peak = (c > 0.2f);
    if (peak) {
#pragma unroll
        for (int j = 0; j < 3; ++j) {
            float r0 = rows[j][x];
            float rl = (x > 0)   ? rows[j][x - 1] : -INFINITY;
            float rr = (x < 255) ? rows[j][x + 1] : -INFINITY;
            if (fmaxf(r0, fmaxf(rl, rr)) > c) peak = false;
        }
    }
    int p = -1;
    if (peak) p = atomicAdd(&lcnt, 1);          // LDS atomic: cheap
    __syncthreads();
    if (x == 0) lbase = lcnt ? atomicAdd(&counts[b * CNT_STRIDE], lcnt) : 0;
    __syncthreads();
    if (peak) {
        int pos = lbase + p;
        if (pos < CAP) {
            int i = y * WC + x;
            unsigned long long key =
                ((unsigned long long)__float_as_uint(c) << 32) |
                (unsigned long long)(0xFFFFFFFFu - (unsigned)i);
            keys[(size_t)b * CAP + pos] = key;
        }
    }
}

// One block per batch: 32 rounds of block-wide argmax (exact top_k semantics),
// then integral refinement (5x5, zero outside) and coordinate mapping.
__global__ __launch_bounds__(256) void topk_refine_kernel(
    const float* __restrict__ cms, unsigned long long* __restrict__ keys,
    const int* __restrict__ counts, float* __restrict__ out_off,
    float* __restrict__ out_vals, float* __restrict__ out_valid,
    float* __restrict__ ws_cx, float* __restrict__ ws_cy,
    float* __restrict__ ws_v) {
    int b = blockIdx.x;
    int tid = threadIdx.x;
    __shared__ unsigned long long rkey[256];
    __shared__ int rpos[256];
    __shared__ unsigned long long sel[KMAX];
    int cnt = counts[b * CNT_STRIDE]; if (cnt > CAP) cnt = CAP;
    unsigned long long* kb = keys + (size_t)b * CAP;

    for (int k = 0; k < KMAX; ++k) {
        unsigned long long best = 0ULL; int bp = -1;
        for (int p = tid; p < cnt; p += 256) {
            unsigned long long kk = kb[p];
            if (kk > best) { best = kk; bp = p; }
        }
        rkey[tid] = best; rpos[tid] = bp;
        __syncthreads();
        for (int s = 128; s > 0; s >>= 1) {
            if (tid < s && rkey[tid + s] > rkey[tid]) {
                rkey[tid] = rkey[tid + s]; rpos[tid] = rpos[tid + s];
            }
            __syncthreads();
        }
        if (tid == 0) { sel[k] = rkey[0]; if (rkey[0]) kb[rpos[0]] = 0ULL; }
        __syncthreads();
    }

    if (tid < KMAX) {
        int k = tid;
        unsigned long long key = sel[k];
        bool valid = key != 0ULL;
        float cx = 80.f, cy = 80.f, val = 0.f;
        if (valid) {
            val = __uint_as_float((unsigned)(key >> 32));
            int idx = (int)(0xFFFFFFFFu - (unsigned)(key & 0xFFFFFFFFULL));
            int py = idx >> 8, px = idx & 255;
            const float* cb = cms + ((size_t)b << 16);
            float gv = 1e-12f, sdx = 0.f, sdy = 0.f;
#pragma unroll
            for (int oy = -2; oy <= 2; ++oy)
#pragma unroll
                for (int ox = -2; ox <= 2; ++ox) {
                    int yy = py + oy, xx = px + ox;
                    if (yy < 0 || yy >= HC || xx < 0 || xx >= WC) continue;
                    float pv = cb[yy * WC + xx];
                    gv += pv; sdx += pv * (float)ox; sdy += pv * (float)oy;
                }
            float dx = sdx / gv, dy = sdy / gv;
            cx = ((float)px + dx) * 4.f;
            cy = ((float)py + dy) * 4.f;
        }
        int o = b * KMAX + k;
        out_off[o * 2 + 0] = cx - 80.f;
        out_off[o * 2 + 1] = cy - 80.f;
        out_vals[o] = val;
        out_valid[o] = valid ? 1.f : 0.f;
        ws_cx[o] = cx; ws_cy[o] = cy; ws_v[o] = valid ? 1.f : 0.f;
    }
}

// 160x160 bilinear crop from full image; zero outside image or for invalid peaks.
__global__ __launch_bounds__(256) void crop_kernel(
    const float* __restrict__ full, const float* __restrict__ ws_cx,
    const float* __restrict__ ws_cy, const float* __restrict__ ws_v,
    float* __restrict__ out_crops) {
    int bidx = blockIdx.x;                      // 512 crops * 100 blocks
    int cid = bidx / 100;
    int pp = (bidx - cid * 100) * 256 + threadIdx.x;   // 0..25599
    int b = cid >> 5;
    float cx = ws_cx[cid], cy = ws_cy[cid], v = ws_v[cid];
    int row = pp / CROPSZ, col = pp - row * CROPSZ;
    float sy = cy - 79.5f + (float)row;
    float sx = cx - 79.5f + (float)col;
    float y0f = floorf(sy), x0f = floorf(sx);
    float wy = sy - y0f, wx = sx - x0f;
    int y0 = (int)y0f, x0 = (int)x0f;
    int yi0 = min(max(y0, 0), HF - 1);
    int yi1 = min(max(y0 + 1, 0), HF - 1);
    int xi0 = min(max(x0, 0), WF - 1);
    int xi1 = min(max(x0 + 1, 0), WF - 1);
    const float* base = full + ((size_t)b << 20);
    float t00 = base[yi0 * WF + xi0];
    float t01 = base[yi0 * WF + xi1];
    float t10 = base[yi1 * WF + xi0];
    float t11 = base[yi1 * WF + xi1];
    float top = t00 * (1.f - wx) + t01 * wx;
    float bot = t10 * (1.f - wx) + t11 * wx;
    float val = top * (1.f - wy) + bot * wy;
    float inr = (sy >= 0.f && sy <= (float)(HF - 1) &&
                 sx >= 0.f && sx <= (float)(WF - 1)) ? 1.f : 0.f;
    out_crops[(size_t)cid * (CROPSZ * CROPSZ) + pp] = val * inr * v;
}

extern "C" void kernel_launch(void* const* d_in, const int* in_sizes, int n_in,
                              void* d_out, int out_size, void* d_ws, size_t ws_size,
                              hipStream_t stream) {
    const float* full = (const float*)d_in[0];
    const float* w1   = (const float*)d_in[1];
    const float* b1   = (const float*)d_in[2];
    const float* w2   = (const float*)d_in[3];
    const float* b2   = (const float*)d_in[4];

    char* ws = (char*)d_ws;
    float* imgs = (float*)(ws + OFF_IMGS);
    float* cms  = (float*)(ws + OFF_CMS);
    unsigned long long* keys = (unsigned long long*)(ws + OFF_KEYS);
    int* counts = (int*)(ws + OFF_CNT);
    float* ws_cx = (float*)(ws + OFF_CX);
    float* ws_cy = (float*)(ws + OFF_CY);
    float* ws_v  = (float*)(ws + OFF_VLD);

    float* out = (float*)d_out;
    float* out_crops = out + OUT_CROPS;
    float* out_off   = out + OUT_OFFS;
    float* out_vals  = out + OUT_VALS;
    float* out_valid = out + OUT_VALID;

    hipLaunchKernelGGL(init_kernel, dim3(1), dim3(256), 0, stream, counts);
    hipLaunchKernelGGL(resize_kernel, dim3(16384), dim3(256), 0, stream, full, imgs);
    hipLaunchKernelGGL(conv_fused_kernel, dim3(256, 16), dim3(256), 0, stream,
                       imgs, w1, b1, w2, b2, cms);
    hipLaunchKernelGGL(peak_scan_kernel, dim3(4096), dim3(256), 0, stream,
                       cms, keys, counts);
    hipLaunchKernelGGL(topk_refine_kernel, dim3(16), dim3(256), 0, stream,
                       cms, keys, counts, out_off, out_vals, out_valid,
                       ws_cx, ws_cy, ws_v);
    hipLaunchKernelGGL(crop_kernel, dim3(51200), dim3(256), 0, stream,
                       full, ws_cx, ws_cy, ws_v, out_crops);
}

// Round 4
// 495.288 us; speedup vs baseline: 3.9379x; 1.4869x over previous
//
#include <hip/hip_runtime.h>
#include <math.h>

#define BATCH 16
#define HF 1024
#define WF 1024
#define HS 512
#define WS2 512
#define HC 256
#define WC 256
#define KMAX 32
#define CAP 16384
#define CROPSZ 160
#define CNT_STRIDE 16

// ---- workspace byte offsets ----
#define OFF_IMGS 0UL                                   // 16*512*512 f32 = 16 MB
#define OFF_CMS  16777216UL                            // 16*256*256 f32 = 4 MB
#define OFF_KEYS 20971520UL                            // 16*16384 u64  = 2 MB
#define OFF_CNT  23068672UL                            // 16*16 int
#define OFF_CX   23070720UL                            // 512 f32
#define OFF_CY   (OFF_CX + 2048UL)
#define OFF_VLD  (OFF_CY + 2048UL)
#define OFF_H    25165824UL                            // h planar-quad: nb*8 MiB

// ---- output element offsets ----
#define OUT_CROPS 0
#define OUT_OFFS  13107200
#define OUT_VALS  13108224
#define OUT_VALID 13108736

// jax.image.resize(bilinear, antialias) at 0.5: 4-tap {1,3,3,1}/8, edge-renorm.
// Also resets the peak counters (block 0).
__global__ __launch_bounds__(256) void resize_kernel(const float* __restrict__ full,
                                                     float* __restrict__ imgs,
                                                     int* __restrict__ counts) {
    if (blockIdx.x == 0 && threadIdx.x < BATCH * CNT_STRIDE) counts[threadIdx.x] = 0;
    int i = blockIdx.x * 256 + threadIdx.x;       // 16*512*512 total
    int x = i & (WS2 - 1);
    int y = (i >> 9) & (HS - 1);
    int b = i >> 18;
    const float w4[4] = {0.125f, 0.375f, 0.375f, 0.125f};
    float wy[4], wx[4];
    int ry[4], rx[4];
    float sy = 0.f, sx = 0.f;
#pragma unroll
    for (int j = 0; j < 4; ++j) {
        int r = 2 * y - 1 + j;
        float w = (r >= 0 && r < HF) ? w4[j] : 0.f;
        wy[j] = w; sy += w;
        ry[j] = r < 0 ? 0 : (r >= HF ? HF - 1 : r);
        int c = 2 * x - 1 + j;
        float wc = (c >= 0 && c < WF) ? w4[j] : 0.f;
        wx[j] = wc; sx += wc;
        rx[j] = c < 0 ? 0 : (c >= WF ? WF - 1 : c);
    }
    float inv = 1.f / (sy * sx);
    const float* base = full + ((size_t)b << 20);
    float acc = 0.f;
#pragma unroll
    for (int j = 0; j < 4; ++j) {
        const float* rp = base + ry[j] * WF;
        float rowacc = 0.f;
#pragma unroll
        for (int ii = 0; ii < 4; ++ii) rowacc += wx[ii] * rp[rx[ii]];
        acc += wy[j] * rowacc;
    }
    imgs[i] = acc * inv;
}

// conv1: 5x5 s2 SAME (1->32) + relu. One thread per output pixel; global reads
// (L1-served); per-channel accumulation in (ky,kx) order — bit-identical chain
// to the validated fused kernel (skipped OOB tap == fma(0,w,z) == z).
// Output planar-quad: hq[(lb*8+q)][y][x] = float4(ch 4q..4q+3).
__global__ __launch_bounds__(256) void conv1_kernel(
    const float* __restrict__ imgs, const float* __restrict__ w1,
    const float* __restrict__ b1, float4* __restrict__ hq) {
    int lb = blockIdx.y;
    int y = blockIdx.x;          // 0..255
    int x = threadIdx.x;         // 0..255
    const float* base = imgs + ((size_t)lb << 18);
    float acc[32];
#pragma unroll
    for (int c = 0; c < 32; ++c) acc[c] = b1[c];
#pragma unroll
    for (int ky = 0; ky < 5; ++ky) {
        int gy = 2 * y - 1 + ky;
        if (gy < 0 || gy >= HS) continue;
        const float* rp = base + gy * WS2;
#pragma unroll
        for (int kx = 0; kx < 5; ++kx) {
            int gx = 2 * x - 1 + kx;
            if (gx < 0 || gx >= WS2) continue;
            float v = rp[gx];
            const float* wp = &w1[(ky * 5 + kx) * 32];
#pragma unroll
            for (int c = 0; c < 32; ++c) acc[c] += v * wp[c];
        }
    }
    size_t o = ((size_t)(lb * 8) << 16) + ((size_t)(y << 8) + x);
#pragma unroll
    for (int q = 0; q < 8; ++q) {
        float4 r;
        r.x = fmaxf(acc[4 * q + 0], 0.f);
        r.y = fmaxf(acc[4 * q + 1], 0.f);
        r.z = fmaxf(acc[4 * q + 2], 0.f);
        r.w = fmaxf(acc[4 * q + 3], 0.f);
        hq[o + ((size_t)q << 16)] = r;
    }
}

// conv2: 5x5 s1 SAME (32->1) + sigmoid. One thread per output pixel; coalesced
// float4 global reads of hq (heavy L1 reuse). Per-quad partial chains in
// (ky,kx,c) order, summed q-ascending, + bias, sigmoid.
__global__ __launch_bounds__(256) void conv2_kernel(
    const float4* __restrict__ hq, const float* __restrict__ w2,
    const float* __restrict__ b2, float* __restrict__ cms, int b_start) {
    int lb = blockIdx.y;
    int y = blockIdx.x;          // 0..255
    int x = threadIdx.x;         // 0..255
    float zq[8];
#pragma unroll
    for (int q = 0; q < 8; ++q) zq[q] = 0.f;
#pragma unroll
    for (int q = 0; q < 8; ++q) {
        const float4* plane = hq + ((size_t)(lb * 8 + q) << 16);
#pragma unroll
        for (int ky = 0; ky < 5; ++ky) {
            int gy = y - 2 + ky;
            if (gy < 0 || gy >= HC) continue;
            const float4* rp = plane + (gy << 8);
#pragma unroll
            for (int kx = 0; kx < 5; ++kx) {
                int gx = x - 2 + kx;
                if (gx < 0 || gx >= WC) continue;
                float4 hv = rp[gx];
                const float* wp = &w2[(ky * 5 + kx) * 32 + 4 * q];
                zq[q] += hv.x * wp[0];
                zq[q] += hv.y * wp[1];
                zq[q] += hv.z * wp[2];
                zq[q] += hv.w * wp[3];
            }
        }
    }
    float z = b2[0];
#pragma unroll
    for (int q = 0; q < 8; ++q) z += zq[q];
    float s = 1.f / (1.f + expf(-z));
    int gb = b_start + lb;
    cms[((size_t)gb << 16) + (y << 8) + x] = s;
}

// Fallback fused conv (used only if ws too small for h buffer) — validated R1/R2.
__global__ __launch_bounds__(256) void conv_fused_kernel(
    const float* __restrict__ imgs, const float* __restrict__ w1,
    const float* __restrict__ b1, const float* __restrict__ w2,
    const float* __restrict__ b2, float* __restrict__ cms) {
    __shared__ float simg[43][43];
    __shared__ float sw1[800];
    __shared__ float sb1[32];
    __shared__ float sh[20 * 20 * 33];
    int tid = threadIdx.x;
    int b = blockIdx.y;
    int ty = blockIdx.x >> 4, tx = blockIdx.x & 15;
    int Y0 = ty << 4, X0 = tx << 4;
    for (int i = tid; i < 800; i += 256) sw1[i] = w1[i];
    if (tid < 32) sb1[tid] = b1[tid];
    int r0 = 2 * Y0 - 5, c0 = 2 * X0 - 5;
    for (int i = tid; i < 43 * 43; i += 256) {
        int r = i / 43, c = i - r * 43;
        int gr = r0 + r, gc = c0 + c;
        float v = 0.f;
        if (gr >= 0 && gr < HS && gc >= 0 && gc < WS2)
            v = imgs[((size_t)b << 18) + gr * WS2 + gc];
        simg[r][c] = v;
    }
    __syncthreads();
    for (int p = tid; p < 400; p += 256) {
        int yy = p / 20, xx = p - yy * 20;
        int yh = Y0 - 2 + yy, xh = X0 - 2 + xx;
        if (yh >= 0 && yh < HC && xh >= 0 && xh < WC) {
            float acc[32];
#pragma unroll
            for (int c = 0; c < 32; ++c) acc[c] = sb1[c];
#pragma unroll
            for (int ky = 0; ky < 5; ++ky)
#pragma unroll
                for (int kx = 0; kx < 5; ++kx) {
                    float v = simg[2 * yy + ky][2 * xx + kx];
                    const float* wp = &sw1[(ky * 5 + kx) * 32];
#pragma unroll
                    for (int c = 0; c < 32; ++c) acc[c] += v * wp[c];
                }
#pragma unroll
            for (int c = 0; c < 32; ++c) sh[p * 33 + c] = fmaxf(acc[c], 0.f);
        } else {
#pragma unroll
            for (int c = 0; c < 32; ++c) sh[p * 33 + c] = 0.f;
        }
    }
    __syncthreads();
    {
        int yy = tid >> 4, xx = tid & 15;
        float z = b2[0];
#pragma unroll
        for (int ky = 0; ky < 5; ++ky)
#pragma unroll
            for (int kx = 0; kx < 5; ++kx) {
                const float* hp = &sh[((yy + ky) * 20 + (xx + kx)) * 33];
                const float* wp = &w2[(ky * 5 + kx) * 32];
#pragma unroll
                for (int c = 0; c < 32; ++c) z += hp[c] * wp[c];
            }
        float s = 1.f / (1.f + expf(-z));
        cms[((size_t)b << 16) + (Y0 + yy) * WC + (X0 + xx)] = s;
    }
}

// 3x3 NMS + threshold; LDS staging, one global atomic per row-block.
__global__ __launch_bounds__(256) void peak_scan_kernel(
    const float* __restrict__ cms, unsigned long long* __restrict__ keys,
    int* __restrict__ counts) {
    int b = blockIdx.x >> 8;
    int y = blockIdx.x & 255;
    int x = threadIdx.x;
    const float* cb = cms + ((size_t)b << 16);
    __shared__ float rows[3][256];
    __shared__ int lcnt, lbase;
    if (x == 0) lcnt = 0;
#pragma unroll
    for (int j = 0; j < 3; ++j) {
        int yy = y - 1 + j;
        rows[j][x] = (yy >= 0 && yy < HC) ? cb[yy * WC + x] : -INFINITY;
    }
    __syncthreads();
    float c = rows[1][x];
    bool peak = (c > 0.2f);
    if (peak) {
#pragma unroll
        for (int j = 0; j < 3; ++j) {
            float r0 = rows[j][x];
            float rl = (x > 0)   ? rows[j][x - 1] : -INFINITY;
            float rr = (x < 255) ? rows[j][x + 1] : -INFINITY;
            if (fmaxf(r0, fmaxf(rl, rr)) > c) peak = false;
        }
    }
    int p = -1;
    if (peak) p = atomicAdd(&lcnt, 1);
    __syncthreads();
    if (x == 0) lbase = lcnt ? atomicAdd(&counts[b * CNT_STRIDE], lcnt) : 0;
    __syncthreads();
    if (peak) {
        int pos = lbase + p;
        if (pos < CAP) {
            int i = y * WC + x;
            unsigned long long key =
                ((unsigned long long)__float_as_uint(c) << 32) |
                (unsigned long long)(0xFFFFFFFFu - (unsigned)i);
            keys[(size_t)b * CAP + pos] = key;
        }
    }
}

__global__ __launch_bounds__(256) void topk_refine_kernel(
    const float* __restrict__ cms, unsigned long long* __restrict__ keys,
    const int* __restrict__ counts, float* __restrict__ out_off,
    float* __restrict__ out_vals, float* __restrict__ out_valid,
    float* __restrict__ ws_cx, float* __restrict__ ws_cy,
    float* __restrict__ ws_v) {
    int b = blockIdx.x;
    int tid = threadIdx.x;
    __shared__ unsigned long long rkey[256];
    __shared__ int rpos[256];
    __shared__ unsigned long long sel[KMAX];
    int cnt = counts[b * CNT_STRIDE]; if (cnt > CAP) cnt = CAP;
    unsigned long long* kb = keys + (size_t)b * CAP;
    for (int k = 0; k < KMAX; ++k) {
        unsigned long long best = 0ULL; int bp = -1;
        for (int p = tid; p < cnt; p += 256) {
            unsigned long long kk = kb[p];
            if (kk > best) { best = kk; bp = p; }
        }
        rkey[tid] = best; rpos[tid] = bp;
        __syncthreads();
        for (int s = 128; s > 0; s >>= 1) {
            if (tid < s && rkey[tid + s] > rkey[tid]) {
                rkey[tid] = rkey[tid + s]; rpos[tid] = rpos[tid + s];
            }
            __syncthreads();
        }
        if (tid == 0) { sel[k] = rkey[0]; if (rkey[0]) kb[rpos[0]] = 0ULL; }
        __syncthreads();
    }
    if (tid < KMAX) {
        int k = tid;
        unsigned long long key = sel[k];
        bool valid = key != 0ULL;
        float cx = 80.f, cy = 80.f, val = 0.f;
        if (valid) {
            val = __uint_as_float((unsigned)(key >> 32));
            int idx = (int)(0xFFFFFFFFu - (unsigned)(key & 0xFFFFFFFFULL));
            int py = idx >> 8, px = idx & 255;
            const float* cb = cms + ((size_t)b << 16);
            float gv = 1e-12f, sdx = 0.f, sdy = 0.f;
#pragma unroll
            for (int oy = -2; oy <= 2; ++oy)
#pragma unroll
                for (int ox = -2; ox <= 2; ++ox) {
                    int yy = py + oy, xx = px + ox;
                    if (yy < 0 || yy >= HC || xx < 0 || xx >= WC) continue;
                    float pv = cb[yy * WC + xx];
                    gv += pv; sdx += pv * (float)ox; sdy += pv * (float)oy;
                }
            float dx = sdx / gv, dy = sdy / gv;
            cx = ((float)px + dx) * 4.f;
            cy = ((float)py + dy) * 4.f;
        }
        int o = b * KMAX + k;
        out_off[o * 2 + 0] = cx - 80.f;
        out_off[o * 2 + 1] = cy - 80.f;
        out_vals[o] = val;
        out_valid[o] = valid ? 1.f : 0.f;
        ws_cx[o] = cx; ws_cy[o] = cy; ws_v[o] = valid ? 1.f : 0.f;
    }
}

__global__ __launch_bounds__(256) void crop_kernel(
    const float* __restrict__ full, const float* __restrict__ ws_cx,
    const float* __restrict__ ws_cy, const float* __restrict__ ws_v,
    float* __restrict__ out_crops) {
    int bidx = blockIdx.x;
    int cid = bidx / 100;
    int pp = (bidx - cid * 100) * 256 + threadIdx.x;
    int b = cid >> 5;
    float cx = ws_cx[cid], cy = ws_cy[cid], v = ws_v[cid];
    int row = pp / CROPSZ, col = pp - row * CROPSZ;
    float sy = cy - 79.5f + (float)row;
    float sx = cx - 79.5f + (float)col;
    float y0f = floorf(sy), x0f = floorf(sx);
    float wy = sy - y0f, wx = sx - x0f;
    int y0 = (int)y0f, x0 = (int)x0f;
    int yi0 = min(max(y0, 0), HF - 1);
    int yi1 = min(max(y0 + 1, 0), HF - 1);
    int xi0 = min(max(x0, 0), WF - 1);
    int xi1 = min(max(x0 + 1, 0), WF - 1);
    const float* base = full + ((size_t)b << 20);
    float t00 = base[yi0 * WF + xi0];
    float t01 = base[yi0 * WF + xi1];
    float t10 = base[yi1 * WF + xi0];
    float t11 = base[yi1 * WF + xi1];
    float top = t00 * (1.f - wx) + t01 * wx;
    float bot = t10 * (1.f - wx) + t11 * wx;
    float val = top * (1.f - wy) + bot * wy;
    float inr = (sy >= 0.f && sy <= (float)(HF - 1) &&
                 sx >= 0.f && sx <= (float)(WF - 1)) ? 1.f : 0.f;
    out_crops[(size_t)cid * (CROPSZ * CROPSZ) + pp] = val * inr * v;
}

extern "C" void kernel_launch(void* const* d_in, const int* in_sizes, int n_in,
                              void* d_out, int out_size, void* d_ws, size_t ws_size,
                              hipStream_t stream) {
    const float* full = (const float*)d_in[0];
    const float* w1   = (const float*)d_in[1];
    const float* b1   = (const float*)d_in[2];
    const float* w2   = (const float*)d_in[3];
    const float* b2   = (const float*)d_in[4];

    char* ws = (char*)d_ws;
    float* imgs = (float*)(ws + OFF_IMGS);
    float* cms  = (float*)(ws + OFF_CMS);
    unsigned long long* keys = (unsigned long long*)(ws + OFF_KEYS);
    int* counts = (int*)(ws + OFF_CNT);
    float* ws_cx = (float*)(ws + OFF_CX);
    float* ws_cy = (float*)(ws + OFF_CY);
    float* ws_v  = (float*)(ws + OFF_VLD);
    float4* hq   = (float4*)(ws + OFF_H);

    float* out = (float*)d_out;
    float* out_crops = out + OUT_CROPS;
    float* out_off   = out + OUT_OFFS;
    float* out_vals  = out + OUT_VALS;
    float* out_valid = out + OUT_VALID;

    hipLaunchKernelGGL(resize_kernel, dim3(16384), dim3(256), 0, stream,
                       full, imgs, counts);

    // h buffer: 8 MiB per batch. Pick batches-per-pass by available workspace.
    int nb = 0;
    const size_t MB = 1048576UL;
    if (ws_size >= OFF_H + 128 * MB)      nb = 16;
    else if (ws_size >= OFF_H + 64 * MB)  nb = 8;
    else if (ws_size >= OFF_H + 32 * MB)  nb = 4;
    else if (ws_size >= OFF_H + 16 * MB)  nb = 2;

    if (nb > 0) {
        for (int b0 = 0; b0 < BATCH; b0 += nb) {
            hipLaunchKernelGGL(conv1_kernel, dim3(256, nb), dim3(256), 0, stream,
                               imgs + ((size_t)b0 << 18), w1, b1, hq);
            hipLaunchKernelGGL(conv2_kernel, dim3(256, nb), dim3(256), 0, stream,
                               hq, w2, b2, cms, b0);
        }
    } else {
        hipLaunchKernelGGL(conv_fused_kernel, dim3(256, 16), dim3(256), 0, stream,
                           imgs, w1, b1, w2, b2, cms);
    }

    hipLaunchKernelGGL(peak_scan_kernel, dim3(4096), dim3(256), 0, stream,
                       cms, keys, counts);
    hipLaunchKernelGGL(topk_refine_kernel, dim3(16), dim3(256), 0, stream,
                       cms, keys, counts, out_off, out_vals, out_valid,
                       ws_cx, ws_cy, ws_v);
    hipLaunchKernelGGL(crop_kernel, dim3(51200), dim3(256), 0, stream,
                       full, ws_cx, ws_cy, ws_v, out_crops);
}

// Round 5
// 381.659 us; speedup vs baseline: 5.1103x; 1.2977x over previous
//
#include <hip/hip_runtime.h>
#include <math.h>

#define BATCH 16
#define HF 1024
#define WF 1024
#define HS 512
#define WS2 512
#define HC 256
#define WC 256
#define KMAX 32
#define CAP 16384
#define CROPSZ 160
#define CNT_STRIDE 16
#define NCHUNK 16
#define CHUNK 1024

// ---- workspace byte offsets ----
#define OFF_IMGS 0UL                                   // 16*512*512 f32 = 16 MB
#define OFF_CMS  16777216UL                            // 16*256*256 f32 = 4 MB
#define OFF_KEYS 20971520UL                            // 16*16384 u64  = 2 MB
#define OFF_CNT  23068672UL                            // 16*16 int
#define OFF_CX   23070720UL                            // 512 f32
#define OFF_CY   (OFF_CX + 2048UL)
#define OFF_VLD  (OFF_CY + 2048UL)
#define OFF_CAND (OFF_VLD + 2048UL)                    // 16*16*32 u64 = 64 KB
#define OFF_H    25165824UL                            // h planar-quad: nb*8 MiB

// ---- output element offsets ----
#define OUT_CROPS 0
#define OUT_OFFS  13107200
#define OUT_VALS  13108224
#define OUT_VALID 13108736

// jax.image.resize(bilinear, antialias) at 0.5: 4-tap {1,3,3,1}/8, edge-renorm.
// Also resets the peak counters (block 0).
__global__ __launch_bounds__(256) void resize_kernel(const float* __restrict__ full,
                                                     float* __restrict__ imgs,
                                                     int* __restrict__ counts) {
    if (blockIdx.x == 0 && threadIdx.x < BATCH * CNT_STRIDE) counts[threadIdx.x] = 0;
    int i = blockIdx.x * 256 + threadIdx.x;       // 16*512*512 total
    int x = i & (WS2 - 1);
    int y = (i >> 9) & (HS - 1);
    int b = i >> 18;
    const float w4[4] = {0.125f, 0.375f, 0.375f, 0.125f};
    float wy[4], wx[4];
    int ry[4], rx[4];
    float sy = 0.f, sx = 0.f;
#pragma unroll
    for (int j = 0; j < 4; ++j) {
        int r = 2 * y - 1 + j;
        float w = (r >= 0 && r < HF) ? w4[j] : 0.f;
        wy[j] = w; sy += w;
        ry[j] = r < 0 ? 0 : (r >= HF ? HF - 1 : r);
        int c = 2 * x - 1 + j;
        float wc = (c >= 0 && c < WF) ? w4[j] : 0.f;
        wx[j] = wc; sx += wc;
        rx[j] = c < 0 ? 0 : (c >= WF ? WF - 1 : c);
    }
    float inv = 1.f / (sy * sx);
    const float* base = full + ((size_t)b << 20);
    float acc = 0.f;
#pragma unroll
    for (int j = 0; j < 4; ++j) {
        const float* rp = base + ry[j] * WF;
        float rowacc = 0.f;
#pragma unroll
        for (int ii = 0; ii < 4; ++ii) rowacc += wx[ii] * rp[rx[ii]];
        acc += wy[j] * rowacc;
    }
    imgs[i] = acc * inv;
}

// conv1: 5x5 s2 SAME (1->32) + relu. One thread per output pixel (validated R4).
// Output planar-quad: hq[(lb*8+q)][y][x] = float4(ch 4q..4q+3).
__global__ __launch_bounds__(256) void conv1_kernel(
    const float* __restrict__ imgs, const float* __restrict__ w1,
    const float* __restrict__ b1, float4* __restrict__ hq) {
    int lb = blockIdx.y;
    int y = blockIdx.x;          // 0..255
    int x = threadIdx.x;         // 0..255
    const float* base = imgs + ((size_t)lb << 18);
    float acc[32];
#pragma unroll
    for (int c = 0; c < 32; ++c) acc[c] = b1[c];
#pragma unroll
    for (int ky = 0; ky < 5; ++ky) {
        int gy = 2 * y - 1 + ky;
        if (gy < 0 || gy >= HS) continue;
        const float* rp = base + gy * WS2;
#pragma unroll
        for (int kx = 0; kx < 5; ++kx) {
            int gx = 2 * x - 1 + kx;
            if (gx < 0 || gx >= WS2) continue;
            float v = rp[gx];
            const float* wp = &w1[(ky * 5 + kx) * 32];
#pragma unroll
            for (int c = 0; c < 32; ++c) acc[c] += v * wp[c];
        }
    }
    size_t o = ((size_t)(lb * 8) << 16) + ((size_t)(y << 8) + x);
#pragma unroll
    for (int q = 0; q < 8; ++q) {
        float4 r;
        r.x = fmaxf(acc[4 * q + 0], 0.f);
        r.y = fmaxf(acc[4 * q + 1], 0.f);
        r.z = fmaxf(acc[4 * q + 2], 0.f);
        r.w = fmaxf(acc[4 * q + 3], 0.f);
        hq[o + ((size_t)q << 16)] = r;
    }
}

// conv2: 5x5 s1 SAME (32->1) + sigmoid. Block = 4 output rows x 256 cols.
// Per quad: stage 8 rows x 260 float4 in LDS (33 KB), lane-stride-1 reads
// (conflict-free). Per-pixel accumulation order IDENTICAL to validated R4:
// q asc -> ky asc -> kx asc -> c asc; per-quad fresh chain; zsum starts at b2.
__global__ __launch_bounds__(256) void conv2_kernel(
    const float4* __restrict__ hq, const float* __restrict__ w2,
    const float* __restrict__ b2, float* __restrict__ cms, int b_start) {
    __shared__ float4 stile[8 * 260];   // rows Y0-2..Y0+5, cols -2..257
    int tid = threadIdx.x;
    int lb = blockIdx.y;
    int Y0 = blockIdx.x << 2;
    int x = tid;
    const float4* w24 = (const float4*)w2;
    float bb = b2[0];
    float zsum[4] = {bb, bb, bb, bb};
    for (int q = 0; q < 8; ++q) {
        const float4* plane = hq + ((size_t)(lb * 8 + q) << 16);
        __syncthreads();
        for (int k = 0; k < 9; ++k) {
            int idx = tid + k * 256;
            if (idx < 8 * 260) {
                int ro = idx / 260, col = idx - ro * 260;
                int gr = Y0 - 2 + ro, gc = col - 2;
                float4 v = make_float4(0.f, 0.f, 0.f, 0.f);
                if (gr >= 0 && gr < HC && gc >= 0 && gc < WC)
                    v = plane[(gr << 8) + gc];
                stile[idx] = v;
            }
        }
        __syncthreads();
        float aq[4] = {0.f, 0.f, 0.f, 0.f};
#pragma unroll
        for (int ro = 0; ro < 8; ++ro) {
            float4 t[5];
#pragma unroll
            for (int kx = 0; kx < 5; ++kx) t[kx] = stile[ro * 260 + x + kx];
#pragma unroll
            for (int r = 0; r < 4; ++r) {
                int ky = ro - r;
                if (ky < 0 || ky > 4) continue;   // resolved at compile time
#pragma unroll
                for (int kx = 0; kx < 5; ++kx) {
                    float4 w = w24[(ky * 5 + kx) * 8 + q];
                    aq[r] += t[kx].x * w.x;
                    aq[r] += t[kx].y * w.y;
                    aq[r] += t[kx].z * w.z;
                    aq[r] += t[kx].w * w.w;
                }
            }
        }
#pragma unroll
        for (int r = 0; r < 4; ++r) zsum[r] += aq[r];
    }
    int gb = b_start + lb;
#pragma unroll
    for (int r = 0; r < 4; ++r) {
        float s = 1.f / (1.f + expf(-zsum[r]));
        cms[((size_t)gb << 16) + ((Y0 + r) << 8) + x] = s;
    }
}

// Fallback fused conv (used only if ws too small for h buffer) — validated R1/R2.
__global__ __launch_bounds__(256) void conv_fused_kernel(
    const float* __restrict__ imgs, const float* __restrict__ w1,
    const float* __restrict__ b1, const float* __restrict__ w2,
    const float* __restrict__ b2, float* __restrict__ cms) {
    __shared__ float simg[43][43];
    __shared__ float sw1[800];
    __shared__ float sb1[32];
    __shared__ float sh[20 * 20 * 33];
    int tid = threadIdx.x;
    int b = blockIdx.y;
    int ty = blockIdx.x >> 4, tx = blockIdx.x & 15;
    int Y0 = ty << 4, X0 = tx << 4;
    for (int i = tid; i < 800; i += 256) sw1[i] = w1[i];
    if (tid < 32) sb1[tid] = b1[tid];
    int r0 = 2 * Y0 - 5, c0 = 2 * X0 - 5;
    for (int i = tid; i < 43 * 43; i += 256) {
        int r = i / 43, c = i - r * 43;
        int gr = r0 + r, gc = c0 + c;
        float v = 0.f;
        if (gr >= 0 && gr < HS && gc >= 0 && gc < WS2)
            v = imgs[((size_t)b << 18) + gr * WS2 + gc];
        simg[r][c] = v;
    }
    __syncthreads();
    for (int p = tid; p < 400; p += 256) {
        int yy = p / 20, xx = p - yy * 20;
        int yh = Y0 - 2 + yy, xh = X0 - 2 + xx;
        if (yh >= 0 && yh < HC && xh >= 0 && xh < WC) {
            float acc[32];
#pragma unroll
            for (int c = 0; c < 32; ++c) acc[c] = sb1[c];
#pragma unroll
            for (int ky = 0; ky < 5; ++ky)
#pragma unroll
                for (int kx = 0; kx < 5; ++kx) {
                    float v = simg[2 * yy + ky][2 * xx + kx];
                    const float* wp = &sw1[(ky * 5 + kx) * 32];
#pragma unroll
                    for (int c = 0; c < 32; ++c) acc[c] += v * wp[c];
                }
#pragma unroll
            for (int c = 0; c < 32; ++c) sh[p * 33 + c] = fmaxf(acc[c], 0.f);
        } else {
#pragma unroll
            for (int c = 0; c < 32; ++c) sh[p * 33 + c] = 0.f;
        }
    }
    __syncthreads();
    {
        int yy = tid >> 4, xx = tid & 15;
        float z = b2[0];
#pragma unroll
        for (int ky = 0; ky < 5; ++ky)
#pragma unroll
            for (int kx = 0; kx < 5; ++kx) {
                const float* hp = &sh[((yy + ky) * 20 + (xx + kx)) * 33];
                const float* wp = &w2[(ky * 5 + kx) * 32];
#pragma unroll
                for (int c = 0; c < 32; ++c) z += hp[c] * wp[c];
            }
        float s = 1.f / (1.f + expf(-z));
        cms[((size_t)b << 16) + (Y0 + yy) * WC + (X0 + xx)] = s;
    }
}

// 3x3 NMS + threshold; LDS staging, one global atomic per row-block.
__global__ __launch_bounds__(256) void peak_scan_kernel(
    const float* __restrict__ cms, unsigned long long* __restrict__ keys,
    int* __restrict__ counts) {
    int b = blockIdx.x >> 8;
    int y = blockIdx.x & 255;
    int x = threadIdx.x;
    const float* cb = cms + ((size_t)b << 16);
    __shared__ float rows[3][256];
    __shared__ int lcnt, lbase;
    if (x == 0) lcnt = 0;
#pragma unroll
    for (int j = 0; j < 3; ++j) {
        int yy = y - 1 + j;
        rows[j][x] = (yy >= 0 && yy < HC) ? cb[yy * WC + x] : -INFINITY;
    }
    __syncthreads();
    float c = rows[1][x];
    bool peak = (c > 0.2f);
    if (peak) {
#pragma unroll
        for (int j = 0; j < 3; ++j) {
            float r0 = rows[j][x];
            float rl = (x > 0)   ? rows[j][x - 1] : -INFINITY;
            float rr = (x < 255) ? rows[j][x + 1] : -INFINITY;
            if (fmaxf(r0, fmaxf(rl, rr)) > c) peak = false;
        }
    }
    int p = -1;
    if (peak) p = atomicAdd(&lcnt, 1);
    __syncthreads();
    if (x == 0) lbase = lcnt ? atomicAdd(&counts[b * CNT_STRIDE], lcnt) : 0;
    __syncthreads();
    if (peak) {
        int pos = lbase + p;
        if (pos < CAP) {
            int i = y * WC + x;
            unsigned long long key =
                ((unsigned long long)__float_as_uint(c) << 32) |
                (unsigned long long)(0xFFFFFFFFu - (unsigned)i);
            keys[(size_t)b * CAP + pos] = key;
        }
    }
}

// Stage A: per (batch, chunk-of-1024) exact top-32 with removal, in LDS.
// Early-exit when chunk exhausted (winner == 0).
__global__ __launch_bounds__(256) void topk_stage_a(
    const unsigned long long* __restrict__ keys, const int* __restrict__ counts,
    unsigned long long* __restrict__ cand) {
    int b = blockIdx.x >> 4;
    int chunk = blockIdx.x & 15;
    int tid = threadIdx.x;
    __shared__ unsigned long long lk[CHUNK];
    __shared__ unsigned long long rkey[256];
    __shared__ int rpos[256];
    int cnt = counts[b * CNT_STRIDE]; if (cnt > CAP) cnt = CAP;
    const unsigned long long* kb = keys + (size_t)b * CAP + chunk * CHUNK;
    int lim = cnt - chunk * CHUNK;
#pragma unroll
    for (int k = 0; k < 4; ++k) {
        int i = tid + k * 256;
        lk[i] = (i < lim) ? kb[i] : 0ULL;
    }
    __syncthreads();
    unsigned long long* out = cand + (size_t)(b * NCHUNK + chunk) * KMAX;
    for (int k = 0; k < KMAX; ++k) {
        unsigned long long best = 0ULL; int bp = -1;
#pragma unroll
        for (int j = 0; j < 4; ++j) {
            int i = tid + j * 256;
            unsigned long long kk = lk[i];
            if (kk > best) { best = kk; bp = i; }
        }
        rkey[tid] = best; rpos[tid] = bp;
        __syncthreads();
        for (int s = 128; s > 0; s >>= 1) {
            if (tid < s && rkey[tid + s] > rkey[tid]) {
                rkey[tid] = rkey[tid + s]; rpos[tid] = rpos[tid + s];
            }
            __syncthreads();
        }
        unsigned long long w = rkey[0];
        if (w == 0ULL) {                       // chunk exhausted: fill rest, done
            if (tid >= k && tid < KMAX) out[tid] = 0ULL;
            break;
        }
        if (tid == 0) { out[k] = w; lk[rpos[0]] = 0ULL; }
        __syncthreads();
    }
}

// Stage B: per batch, exact top-32 over the 512 candidates, then integral
// refinement (verbatim R4 tail) and coordinate mapping.
__global__ __launch_bounds__(256) void topk_stage_b(
    const float* __restrict__ cms, const unsigned long long* __restrict__ cand,
    float* __restrict__ out_off, float* __restrict__ out_vals,
    float* __restrict__ out_valid, float* __restrict__ ws_cx,
    float* __restrict__ ws_cy, float* __restrict__ ws_v) {
    int b = blockIdx.x;
    int tid = threadIdx.x;
    __shared__ unsigned long long lk[NCHUNK * KMAX];   // 512
    __shared__ unsigned long long rkey[256];
    __shared__ int rpos[256];
    __shared__ unsigned long long sel[KMAX];
    lk[tid]       = cand[(size_t)b * 512 + tid];
    lk[tid + 256] = cand[(size_t)b * 512 + 256 + tid];
    if (tid < KMAX) sel[tid] = 0ULL;
    __syncthreads();
    for (int k = 0; k < KMAX; ++k) {
        unsigned long long best = 0ULL; int bp = -1;
        {
            unsigned long long k0 = lk[tid], k1 = lk[tid + 256];
            if (k0 > best) { best = k0; bp = tid; }
            if (k1 > best) { best = k1; bp = tid + 256; }
        }
        rkey[tid] = best; rpos[tid] = bp;
        __syncthreads();
        for (int s = 128; s > 0; s >>= 1) {
            if (tid < s && rkey[tid + s] > rkey[tid]) {
                rkey[tid] = rkey[tid + s]; rpos[tid] = rpos[tid + s];
            }
            __syncthreads();
        }
        unsigned long long w = rkey[0];
        if (w == 0ULL) break;                  // sel pre-zeroed
        if (tid == 0) { sel[k] = w; lk[rpos[0]] = 0ULL; }
        __syncthreads();
    }
    __syncthreads();
    if (tid < KMAX) {
        int k = tid;
        unsigned long long key = sel[k];
        bool valid = key != 0ULL;
        float cx = 80.f, cy = 80.f, val = 0.f;
        if (valid) {
            val = __uint_as_float((unsigned)(key >> 32));
            int idx = (int)(0xFFFFFFFFu - (unsigned)(key & 0xFFFFFFFFULL));
            int py = idx >> 8, px = idx & 255;
            const float* cb = cms + ((size_t)b << 16);
            float gv = 1e-12f, sdx = 0.f, sdy = 0.f;
#pragma unroll
            for (int oy = -2; oy <= 2; ++oy)
#pragma unroll
                for (int ox = -2; ox <= 2; ++ox) {
                    int yy = py + oy, xx = px + ox;
                    if (yy < 0 || yy >= HC || xx < 0 || xx >= WC) continue;
                    float pv = cb[yy * WC + xx];
                    gv += pv; sdx += pv * (float)ox; sdy += pv * (float)oy;
                }
            float dx = sdx / gv, dy = sdy / gv;
            cx = ((float)px + dx) * 4.f;
            cy = ((float)py + dy) * 4.f;
        }
        int o = b * KMAX + k;
        out_off[o * 2 + 0] = cx - 80.f;
        out_off[o * 2 + 1] = cy - 80.f;
        out_vals[o] = val;
        out_valid[o] = valid ? 1.f : 0.f;
        ws_cx[o] = cx; ws_cy[o] = cy; ws_v[o] = valid ? 1.f : 0.f;
    }
}

__global__ __launch_bounds__(256) void crop_kernel(
    const float* __restrict__ full, const float* __restrict__ ws_cx,
    const float* __restrict__ ws_cy, const float* __restrict__ ws_v,
    float* __restrict__ out_crops) {
    int bidx = blockIdx.x;
    int cid = bidx / 100;
    int pp = (bidx - cid * 100) * 256 + threadIdx.x;
    int b = cid >> 5;
    float cx = ws_cx[cid], cy = ws_cy[cid], v = ws_v[cid];
    int row = pp / CROPSZ, col = pp - row * CROPSZ;
    float sy = cy - 79.5f + (float)row;
    float sx = cx - 79.5f + (float)col;
    float y0f = floorf(sy), x0f = floorf(sx);
    float wy = sy - y0f, wx = sx - x0f;
    int y0 = (int)y0f, x0 = (int)x0f;
    int yi0 = min(max(y0, 0), HF - 1);
    int yi1 = min(max(y0 + 1, 0), HF - 1);
    int xi0 = min(max(x0, 0), WF - 1);
    int xi1 = min(max(x0 + 1, 0), WF - 1);
    const float* base = full + ((size_t)b << 20);
    float t00 = base[yi0 * WF + xi0];
    float t01 = base[yi0 * WF + xi1];
    float t10 = base[yi1 * WF + xi0];
    float t11 = base[yi1 * WF + xi1];
    float top = t00 * (1.f - wx) + t01 * wx;
    float bot = t10 * (1.f - wx) + t11 * wx;
    float val = top * (1.f - wy) + bot * wy;
    float inr = (sy >= 0.f && sy <= (float)(HF - 1) &&
                 sx >= 0.f && sx <= (float)(WF - 1)) ? 1.f : 0.f;
    out_crops[(size_t)cid * (CROPSZ * CROPSZ) + pp] = val * inr * v;
}

extern "C" void kernel_launch(void* const* d_in, const int* in_sizes, int n_in,
                              void* d_out, int out_size, void* d_ws, size_t ws_size,
                              hipStream_t stream) {
    const float* full = (const float*)d_in[0];
    const float* w1   = (const float*)d_in[1];
    const float* b1   = (const float*)d_in[2];
    const float* w2   = (const float*)d_in[3];
    const float* b2   = (const float*)d_in[4];

    char* ws = (char*)d_ws;
    float* imgs = (float*)(ws + OFF_IMGS);
    float* cms  = (float*)(ws + OFF_CMS);
    unsigned long long* keys = (unsigned long long*)(ws + OFF_KEYS);
    int* counts = (int*)(ws + OFF_CNT);
    float* ws_cx = (float*)(ws + OFF_CX);
    float* ws_cy = (float*)(ws + OFF_CY);
    float* ws_v  = (float*)(ws + OFF_VLD);
    unsigned long long* cand = (unsigned long long*)(ws + OFF_CAND);
    float4* hq   = (float4*)(ws + OFF_H);

    float* out = (float*)d_out;
    float* out_crops = out + OUT_CROPS;
    float* out_off   = out + OUT_OFFS;
    float* out_vals  = out + OUT_VALS;
    float* out_valid = out + OUT_VALID;

    hipLaunchKernelGGL(resize_kernel, dim3(16384), dim3(256), 0, stream,
                       full, imgs, counts);

    int nb = 0;
    const size_t MB = 1048576UL;
    if (ws_size >= OFF_H + 128 * MB)      nb = 16;
    else if (ws_size >= OFF_H + 64 * MB)  nb = 8;
    else if (ws_size >= OFF_H + 32 * MB)  nb = 4;
    else if (ws_size >= OFF_H + 16 * MB)  nb = 2;

    if (nb > 0) {
        for (int b0 = 0; b0 < BATCH; b0 += nb) {
            hipLaunchKernelGGL(conv1_kernel, dim3(256, nb), dim3(256), 0, stream,
                               imgs + ((size_t)b0 << 18), w1, b1, hq);
            hipLaunchKernelGGL(conv2_kernel, dim3(64, nb), dim3(256), 0, stream,
                               hq, w2, b2, cms, b0);
        }
    } else {
        hipLaunchKernelGGL(conv_fused_kernel, dim3(256, 16), dim3(256), 0, stream,
                           imgs, w1, b1, w2, b2, cms);
    }

    hipLaunchKernelGGL(peak_scan_kernel, dim3(4096), dim3(256), 0, stream,
                       cms, keys, counts);
    hipLaunchKernelGGL(topk_stage_a, dim3(256), dim3(256), 0, stream,
                       keys, counts, cand);
    hipLaunchKernelGGL(topk_stage_b, dim3(16), dim3(256), 0, stream,
                       cms, cand, out_off, out_vals, out_valid,
                       ws_cx, ws_cy, ws_v);
    hipLaunchKernelGGL(crop_kernel, dim3(51200), dim3(256), 0, stream,
                       full, ws_cx, ws_cy, ws_v, out_crops);
}

// Round 6
// 348.113 us; speedup vs baseline: 5.6027x; 1.0964x over previous
//
#include <hip/hip_runtime.h>
#include <math.h>

#define BATCH 16
#define HF 1024
#define WF 1024
#define HS 512
#define WS2 512
#define HC 256
#define WC 256
#define KMAX 32
#define CAP 16384
#define CROPSZ 160
#define CNT_STRIDE 16
#define NCHUNK 16
#define CHUNK 1024

// ---- workspace byte offsets ----
#define OFF_IMGS 0UL                                   // 16*512*512 f32 = 16 MB
#define OFF_CMS  16777216UL                            // 16*256*256 f32 = 4 MB
#define OFF_KEYS 20971520UL                            // 16*16384 u64  = 2 MB
#define OFF_CNT  23068672UL                            // 16*16 int
#define OFF_CX   23070720UL                            // 512 f32
#define OFF_CY   (OFF_CX + 2048UL)
#define OFF_VLD  (OFF_CY + 2048UL)
#define OFF_CAND (OFF_VLD + 2048UL)                    // 16*16*32 u64 = 64 KB
#define OFF_H    25165824UL                            // h planar-quad: nb*8 MiB

// ---- output element offsets ----
#define OUT_CROPS 0
#define OUT_OFFS  13107200
#define OUT_VALS  13108224
#define OUT_VALID 13108736

// jax.image.resize(bilinear, antialias) at 0.5: 4-tap {1,3,3,1}/8, edge-renorm.
// Block = one output row (2 px/thread); the 4 source rows staged in LDS via
// coalesced float4 loads. Also resets the peak counters (block (0,0)).
__global__ __launch_bounds__(256) void resize_kernel(const float* __restrict__ full,
                                                     float* __restrict__ imgs,
                                                     int* __restrict__ counts) {
    if (blockIdx.x == 0 && blockIdx.y == 0 && threadIdx.x < BATCH * CNT_STRIDE)
        counts[threadIdx.x] = 0;
    __shared__ float simg[4][1024];
    int tid = threadIdx.x;
    int y = blockIdx.x;          // 0..511
    int b = blockIdx.y;
    const float w4[4] = {0.125f, 0.375f, 0.375f, 0.125f};
    float wy[4];
    int ry[4];
    float sy = 0.f;
#pragma unroll
    for (int j = 0; j < 4; ++j) {
        int r = 2 * y - 1 + j;
        float w = (r >= 0 && r < HF) ? w4[j] : 0.f;
        wy[j] = w; sy += w;
        ry[j] = r < 0 ? 0 : (r >= HF ? HF - 1 : r);
    }
    const float* base = full + ((size_t)b << 20);
#pragma unroll
    for (int j = 0; j < 4; ++j) {
        const float4* rp4 = (const float4*)(base + ry[j] * WF);
        ((float4*)simg[j])[tid] = rp4[tid];
    }
    __syncthreads();
#pragma unroll
    for (int p = 0; p < 2; ++p) {
        int x = tid + 256 * p;
        float wx[4];
        int rx[4];
        float sx = 0.f;
#pragma unroll
        for (int ii = 0; ii < 4; ++ii) {
            int c = 2 * x - 1 + ii;
            float wc = (c >= 0 && c < WF) ? w4[ii] : 0.f;
            wx[ii] = wc; sx += wc;
            rx[ii] = c < 0 ? 0 : (c >= WF ? WF - 1 : c);
        }
        float inv = 1.f / (sy * sx);
        float acc = 0.f;
#pragma unroll
        for (int j = 0; j < 4; ++j) {
            float rowacc = 0.f;
#pragma unroll
            for (int ii = 0; ii < 4; ++ii) rowacc += wx[ii] * simg[j][rx[ii]];
            acc += wy[j] * rowacc;
        }
        imgs[((size_t)b << 18) + (y << 9) + x] = acc * inv;
    }
}

// conv1: 5x5 s2 SAME (1->32) + relu. One thread per output pixel (validated R4).
// Output planar-quad: hq[(lb*8+q)][y][x] = float4(ch 4q..4q+3).
__global__ __launch_bounds__(256) void conv1_kernel(
    const float* __restrict__ imgs, const float* __restrict__ w1,
    const float* __restrict__ b1, float4* __restrict__ hq) {
    int lb = blockIdx.y;
    int y = blockIdx.x;          // 0..255
    int x = threadIdx.x;         // 0..255
    const float* base = imgs + ((size_t)lb << 18);
    float acc[32];
#pragma unroll
    for (int c = 0; c < 32; ++c) acc[c] = b1[c];
#pragma unroll
    for (int ky = 0; ky < 5; ++ky) {
        int gy = 2 * y - 1 + ky;
        if (gy < 0 || gy >= HS) continue;
        const float* rp = base + gy * WS2;
#pragma unroll
        for (int kx = 0; kx < 5; ++kx) {
            int gx = 2 * x - 1 + kx;
            if (gx < 0 || gx >= WS2) continue;
            float v = rp[gx];
            const float* wp = &w1[(ky * 5 + kx) * 32];
#pragma unroll
            for (int c = 0; c < 32; ++c) acc[c] += v * wp[c];
        }
    }
    size_t o = ((size_t)(lb * 8) << 16) + ((size_t)(y << 8) + x);
#pragma unroll
    for (int q = 0; q < 8; ++q) {
        float4 r;
        r.x = fmaxf(acc[4 * q + 0], 0.f);
        r.y = fmaxf(acc[4 * q + 1], 0.f);
        r.z = fmaxf(acc[4 * q + 2], 0.f);
        r.w = fmaxf(acc[4 * q + 3], 0.f);
        hq[o + ((size_t)q << 16)] = r;
    }
}

// conv2: 5x5 s1 SAME (32->1) + sigmoid. Register sliding-window, no LDS, no
// barriers. Thread = column x, 8 output rows Y0..Y0+7. Per quad, walk the 12
// input rows once (5 overlapping float4 loads each, lane-coalesced); row rr
// feeds output rows j in [rr-4, rr] with ky = rr - j (compile-time bounds).
// Skipped OOB rows/cols == zero-padding exactly.
__global__ __launch_bounds__(256) void conv2_kernel(
    const float4* __restrict__ hq, const float* __restrict__ w2,
    const float* __restrict__ b2, float* __restrict__ cms, int b_start) {
    int x = threadIdx.x;             // 0..255
    int lb = blockIdx.y;
    int Y0 = blockIdx.x << 3;        // 8 output rows per thread
    const float4* w24 = (const float4*)w2;
    float bb = b2[0];
    float z[8];
#pragma unroll
    for (int j = 0; j < 8; ++j) z[j] = bb;
    for (int q = 0; q < 8; ++q) {
        const float4* plane = hq + ((size_t)(lb * 8 + q) << 16);
#pragma unroll
        for (int rr = 0; rr < 12; ++rr) {
            int gr = Y0 - 2 + rr;
            if (gr < 0 || gr >= HC) continue;     // uniform scalar branch
            const float4* rp = plane + (gr << 8);
            float4 t[5];
#pragma unroll
            for (int kx = 0; kx < 5; ++kx) {
                int gx = x - 2 + kx;
                t[kx] = (gx >= 0 && gx < WC) ? rp[gx]
                                             : make_float4(0.f, 0.f, 0.f, 0.f);
            }
#pragma unroll
            for (int j = 0; j < 8; ++j) {
                int ky = rr - j;                  // compile-time per (rr,j)
                if (ky < 0 || ky > 4) continue;
#pragma unroll
                for (int kx = 0; kx < 5; ++kx) {
                    float4 w = w24[(ky * 5 + kx) * 8 + q];
                    z[j] += t[kx].x * w.x;
                    z[j] += t[kx].y * w.y;
                    z[j] += t[kx].z * w.z;
                    z[j] += t[kx].w * w.w;
                }
            }
        }
    }
    int gb = b_start + lb;
#pragma unroll
    for (int j = 0; j < 8; ++j) {
        float s = 1.f / (1.f + expf(-z[j]));
        cms[((size_t)gb << 16) + ((Y0 + j) << 8) + x] = s;
    }
}

// Fallback fused conv (used only if ws too small for h buffer) — validated R1/R2.
__global__ __launch_bounds__(256) void conv_fused_kernel(
    const float* __restrict__ imgs, const float* __restrict__ w1,
    const float* __restrict__ b1, const float* __restrict__ w2,
    const float* __restrict__ b2, float* __restrict__ cms) {
    __shared__ float simg[43][43];
    __shared__ float sw1[800];
    __shared__ float sb1[32];
    __shared__ float sh[20 * 20 * 33];
    int tid = threadIdx.x;
    int b = blockIdx.y;
    int ty = blockIdx.x >> 4, tx = blockIdx.x & 15;
    int Y0 = ty << 4, X0 = tx << 4;
    for (int i = tid; i < 800; i += 256) sw1[i] = w1[i];
    if (tid < 32) sb1[tid] = b1[tid];
    int r0 = 2 * Y0 - 5, c0 = 2 * X0 - 5;
    for (int i = tid; i < 43 * 43; i += 256) {
        int r = i / 43, c = i - r * 43;
        int gr = r0 + r, gc = c0 + c;
        float v = 0.f;
        if (gr >= 0 && gr < HS && gc >= 0 && gc < WS2)
            v = imgs[((size_t)b << 18) + gr * WS2 + gc];
        simg[r][c] = v;
    }
    __syncthreads();
    for (int p = tid; p < 400; p += 256) {
        int yy = p / 20, xx = p - yy * 20;
        int yh = Y0 - 2 + yy, xh = X0 - 2 + xx;
        if (yh >= 0 && yh < HC && xh >= 0 && xh < WC) {
            float acc[32];
#pragma unroll
            for (int c = 0; c < 32; ++c) acc[c] = sb1[c];
#pragma unroll
            for (int ky = 0; ky < 5; ++ky)
#pragma unroll
                for (int kx = 0; kx < 5; ++kx) {
                    float v = simg[2 * yy + ky][2 * xx + kx];
                    const float* wp = &sw1[(ky * 5 + kx) * 32];
#pragma unroll
                    for (int c = 0; c < 32; ++c) acc[c] += v * wp[c];
                }
#pragma unroll
            for (int c = 0; c < 32; ++c) sh[p * 33 + c] = fmaxf(acc[c], 0.f);
        } else {
#pragma unroll
            for (int c = 0; c < 32; ++c) sh[p * 33 + c] = 0.f;
        }
    }
    __syncthreads();
    {
        int yy = tid >> 4, xx = tid & 15;
        float z = b2[0];
#pragma unroll
        for (int ky = 0; ky < 5; ++ky)
#pragma unroll
            for (int kx = 0; kx < 5; ++kx) {
                const float* hp = &sh[((yy + ky) * 20 + (xx + kx)) * 33];
                const float* wp = &w2[(ky * 5 + kx) * 32];
#pragma unroll
                for (int c = 0; c < 32; ++c) z += hp[c] * wp[c];
            }
        float s = 1.f / (1.f + expf(-z));
        cms[((size_t)b << 16) + (Y0 + yy) * WC + (X0 + xx)] = s;
    }
}

// 3x3 NMS + threshold; LDS staging, one global atomic per row-block.
__global__ __launch_bounds__(256) void peak_scan_kernel(
    const float* __restrict__ cms, unsigned long long* __restrict__ keys,
    int* __restrict__ counts) {
    int b = blockIdx.x >> 8;
    int y = blockIdx.x & 255;
    int x = threadIdx.x;
    const float* cb = cms + ((size_t)b << 16);
    __shared__ float rows[3][256];
    __shared__ int lcnt, lbase;
    if (x == 0) lcnt = 0;
#pragma unroll
    for (int j = 0; j < 3; ++j) {
        int yy = y - 1 + j;
        rows[j][x] = (yy >= 0 && yy < HC) ? cb[yy * WC + x] : -INFINITY;
    }
    __syncthreads();
    float c = rows[1][x];
    bool peak = (c > 0.2f);
    if (peak) {
#pragma unroll
        for (int j = 0; j < 3; ++j) {
            float r0 = rows[j][x];
            float rl = (x > 0)   ? rows[j][x - 1] : -INFINITY;
            float rr = (x < 255) ? rows[j][x + 1] : -INFINITY;
            if (fmaxf(r0, fmaxf(rl, rr)) > c) peak = false;
        }
    }
    int p = -1;
    if (peak) p = atomicAdd(&lcnt, 1);
    __syncthreads();
    if (x == 0) lbase = lcnt ? atomicAdd(&counts[b * CNT_STRIDE], lcnt) : 0;
    __syncthreads();
    if (peak) {
        int pos = lbase + p;
        if (pos < CAP) {
            int i = y * WC + x;
            unsigned long long key =
                ((unsigned long long)__float_as_uint(c) << 32) |
                (unsigned long long)(0xFFFFFFFFu - (unsigned)i);
            keys[(size_t)b * CAP + pos] = key;
        }
    }
}

// Stage A: per (batch, chunk-of-1024) exact top-32 with removal, in LDS.
__global__ __launch_bounds__(256) void topk_stage_a(
    const unsigned long long* __restrict__ keys, const int* __restrict__ counts,
    unsigned long long* __restrict__ cand) {
    int b = blockIdx.x >> 4;
    int chunk = blockIdx.x & 15;
    int tid = threadIdx.x;
    __shared__ unsigned long long lk[CHUNK];
    __shared__ unsigned long long rkey[256];
    __shared__ int rpos[256];
    int cnt = counts[b * CNT_STRIDE]; if (cnt > CAP) cnt = CAP;
    const unsigned long long* kb = keys + (size_t)b * CAP + chunk * CHUNK;
    int lim = cnt - chunk * CHUNK;
#pragma unroll
    for (int k = 0; k < 4; ++k) {
        int i = tid + k * 256;
        lk[i] = (i < lim) ? kb[i] : 0ULL;
    }
    __syncthreads();
    unsigned long long* out = cand + (size_t)(b * NCHUNK + chunk) * KMAX;
    for (int k = 0; k < KMAX; ++k) {
        unsigned long long best = 0ULL; int bp = -1;
#pragma unroll
        for (int j = 0; j < 4; ++j) {
            int i = tid + j * 256;
            unsigned long long kk = lk[i];
            if (kk > best) { best = kk; bp = i; }
        }
        rkey[tid] = best; rpos[tid] = bp;
        __syncthreads();
        for (int s = 128; s > 0; s >>= 1) {
            if (tid < s && rkey[tid + s] > rkey[tid]) {
                rkey[tid] = rkey[tid + s]; rpos[tid] = rpos[tid + s];
            }
            __syncthreads();
        }
        unsigned long long w = rkey[0];
        if (w == 0ULL) {
            if (tid >= k && tid < KMAX) out[tid] = 0ULL;
            break;
        }
        if (tid == 0) { out[k] = w; lk[rpos[0]] = 0ULL; }
        __syncthreads();
    }
}

// Stage B: per batch, exact top-32 over 512 candidates + integral refinement.
__global__ __launch_bounds__(256) void topk_stage_b(
    const float* __restrict__ cms, const unsigned long long* __restrict__ cand,
    float* __restrict__ out_off, float* __restrict__ out_vals,
    float* __restrict__ out_valid, float* __restrict__ ws_cx,
    float* __restrict__ ws_cy, float* __restrict__ ws_v) {
    int b = blockIdx.x;
    int tid = threadIdx.x;
    __shared__ unsigned long long lk[NCHUNK * KMAX];   // 512
    __shared__ unsigned long long rkey[256];
    __shared__ int rpos[256];
    __shared__ unsigned long long sel[KMAX];
    lk[tid]       = cand[(size_t)b * 512 + tid];
    lk[tid + 256] = cand[(size_t)b * 512 + 256 + tid];
    if (tid < KMAX) sel[tid] = 0ULL;
    __syncthreads();
    for (int k = 0; k < KMAX; ++k) {
        unsigned long long best = 0ULL; int bp = -1;
        {
            unsigned long long k0 = lk[tid], k1 = lk[tid + 256];
            if (k0 > best) { best = k0; bp = tid; }
            if (k1 > best) { best = k1; bp = tid + 256; }
        }
        rkey[tid] = best; rpos[tid] = bp;
        __syncthreads();
        for (int s = 128; s > 0; s >>= 1) {
            if (tid < s && rkey[tid + s] > rkey[tid]) {
                rkey[tid] = rkey[tid + s]; rpos[tid] = rpos[tid + s];
            }
            __syncthreads();
        }
        unsigned long long w = rkey[0];
        if (w == 0ULL) break;
        if (tid == 0) { sel[k] = w; lk[rpos[0]] = 0ULL; }
        __syncthreads();
    }
    __syncthreads();
    if (tid < KMAX) {
        int k = tid;
        unsigned long long key = sel[k];
        bool valid = key != 0ULL;
        float cx = 80.f, cy = 80.f, val = 0.f;
        if (valid) {
            val = __uint_as_float((unsigned)(key >> 32));
            int idx = (int)(0xFFFFFFFFu - (unsigned)(key & 0xFFFFFFFFULL));
            int py = idx >> 8, px = idx & 255;
            const float* cb = cms + ((size_t)b << 16);
            float gv = 1e-12f, sdx = 0.f, sdy = 0.f;
#pragma unroll
            for (int oy = -2; oy <= 2; ++oy)
#pragma unroll
                for (int ox = -2; ox <= 2; ++ox) {
                    int yy = py + oy, xx = px + ox;
                    if (yy < 0 || yy >= HC || xx < 0 || xx >= WC) continue;
                    float pv = cb[yy * WC + xx];
                    gv += pv; sdx += pv * (float)ox; sdy += pv * (float)oy;
                }
            float dx = sdx / gv, dy = sdy / gv;
            cx = ((float)px + dx) * 4.f;
            cy = ((float)py + dy) * 4.f;
        }
        int o = b * KMAX + k;
        out_off[o * 2 + 0] = cx - 80.f;
        out_off[o * 2 + 1] = cy - 80.f;
        out_vals[o] = val;
        out_valid[o] = valid ? 1.f : 0.f;
        ws_cx[o] = cx; ws_cy[o] = cy; ws_v[o] = valid ? 1.f : 0.f;
    }
}

__global__ __launch_bounds__(256) void crop_kernel(
    const float* __restrict__ full, const float* __restrict__ ws_cx,
    const float* __restrict__ ws_cy, const float* __restrict__ ws_v,
    float* __restrict__ out_crops) {
    int bidx = blockIdx.x;
    int cid = bidx / 100;
    int pp = (bidx - cid * 100) * 256 + threadIdx.x;
    int b = cid >> 5;
    float cx = ws_cx[cid], cy = ws_cy[cid], v = ws_v[cid];
    int row = pp / CROPSZ, col = pp - row * CROPSZ;
    float sy = cy - 79.5f + (float)row;
    float sx = cx - 79.5f + (float)col;
    float y0f = floorf(sy), x0f = floorf(sx);
    float wy = sy - y0f, wx = sx - x0f;
    int y0 = (int)y0f, x0 = (int)x0f;
    int yi0 = min(max(y0, 0), HF - 1);
    int yi1 = min(max(y0 + 1, 0), HF - 1);
    int xi0 = min(max(x0, 0), WF - 1);
    int xi1 = min(max(x0 + 1, 0), WF - 1);
    const float* base = full + ((size_t)b << 20);
    float t00 = base[yi0 * WF + xi0];
    float t01 = base[yi0 * WF + xi1];
    float t10 = base[yi1 * WF + xi0];
    float t11 = base[yi1 * WF + xi1];
    float top = t00 * (1.f - wx) + t01 * wx;
    float bot = t10 * (1.f - wx) + t11 * wx;
    float val = top * (1.f - wy) + bot * wy;
    float inr = (sy >= 0.f && sy <= (float)(HF - 1) &&
                 sx >= 0.f && sx <= (float)(WF - 1)) ? 1.f : 0.f;
    out_crops[(size_t)cid * (CROPSZ * CROPSZ) + pp] = val * inr * v;
}

extern "C" void kernel_launch(void* const* d_in, const int* in_sizes, int n_in,
                              void* d_out, int out_size, void* d_ws, size_t ws_size,
                              hipStream_t stream) {
    const float* full = (const float*)d_in[0];
    const float* w1   = (const float*)d_in[1];
    const float* b1   = (const float*)d_in[2];
    const float* w2   = (const float*)d_in[3];
    const float* b2   = (const float*)d_in[4];

    char* ws = (char*)d_ws;
    float* imgs = (float*)(ws + OFF_IMGS);
    float* cms  = (float*)(ws + OFF_CMS);
    unsigned long long* keys = (unsigned long long*)(ws + OFF_KEYS);
    int* counts = (int*)(ws + OFF_CNT);
    float* ws_cx = (float*)(ws + OFF_CX);
    float* ws_cy = (float*)(ws + OFF_CY);
    float* ws_v  = (float*)(ws + OFF_VLD);
    unsigned long long* cand = (unsigned long long*)(ws + OFF_CAND);
    float4* hq   = (float4*)(ws + OFF_H);

    float* out = (float*)d_out;
    float* out_crops = out + OUT_CROPS;
    float* out_off   = out + OUT_OFFS;
    float* out_vals  = out + OUT_VALS;
    float* out_valid = out + OUT_VALID;

    hipLaunchKernelGGL(resize_kernel, dim3(512, 16), dim3(256), 0, stream,
                       full, imgs, counts);

    int nb = 0;
    const size_t MB = 1048576UL;
    if (ws_size >= OFF_H + 128 * MB)      nb = 16;
    else if (ws_size >= OFF_H + 64 * MB)  nb = 8;
    else if (ws_size >= OFF_H + 32 * MB)  nb = 4;
    else if (ws_size >= OFF_H + 16 * MB)  nb = 2;

    if (nb > 0) {
        for (int b0 = 0; b0 < BATCH; b0 += nb) {
            hipLaunchKernelGGL(conv1_kernel, dim3(256, nb), dim3(256), 0, stream,
                               imgs + ((size_t)b0 << 18), w1, b1, hq);
            hipLaunchKernelGGL(conv2_kernel, dim3(32, nb), dim3(256), 0, stream,
                               hq, w2, b2, cms, b0);
        }
    } else {
        hipLaunchKernelGGL(conv_fused_kernel, dim3(256, 16), dim3(256), 0, stream,
                           imgs, w1, b1, w2, b2, cms);
    }

    hipLaunchKernelGGL(peak_scan_kernel, dim3(4096), dim3(256), 0, stream,
                       cms, keys, counts);
    hipLaunchKernelGGL(topk_stage_a, dim3(256), dim3(256), 0, stream,
                       keys, counts, cand);
    hipLaunchKernelGGL(topk_stage_b, dim3(16), dim3(256), 0, stream,
                       cms, cand, out_off, out_vals, out_valid,
                       ws_cx, ws_cy, ws_v);
    hipLaunchKernelGGL(crop_kernel, dim3(51200), dim3(256), 0, stream,
                       full, ws_cx, ws_cy, ws_v, out_crops);
}